// Round 4
// baseline (176.842 us; speedup 1.0000x reference)
//
#include <hip/hip_runtime.h>

#define NC_MEM 64
#define NC_IMG 64
#define NC     128
#define B_     32
#define H_     64
#define W_     96
#define HW_    (H_ * W_)      // 6144
#define P_TILE 128
#define NTILES (HW_ / P_TILE) // 48
#define FS     520            // frag stride in ushorts: 512 + 8 pad (16B) -> staggers pt banks
#define FOFF(pt, ks) ((((pt) * 4) + (ks)) * FS)

// d_ws byte layout
#define WA_HI  0                       // ushort[3][8][4][64][8] = 98304 B (bf16 hi, A-fragment order)
#define WA_LO  98304                   // same, bf16 lo
#define XF_OFF 196608                  // float[32][16]
#define UM_OFF 198656                  // float[32]

typedef __attribute__((ext_vector_type(8))) short bf16x8;
typedef __attribute__((ext_vector_type(4))) float f32x4;

__device__ inline unsigned short f2bf_rn(float x) {
    unsigned u = __float_as_uint(x);
    return (unsigned short)((u + 0x7FFFu + ((u >> 16) & 1u)) >> 16);
}
__device__ inline float bf2f(unsigned short h) {
    return __uint_as_float(((unsigned)h) << 16);
}

// ---------------------------------------------------------------------------
// prep: blocks 0..191 split W into bf16 hi/lo in MFMA A-fragment order;
// block 192 computes xf via closed-form adjugate inverse + decodes use_memory.
// ---------------------------------------------------------------------------
__global__ void prep(const float* __restrict__ Ws,
                     const float* __restrict__ prev_ext,
                     const float* __restrict__ cur_ext,
                     const int* __restrict__ mem_idx,
                     const unsigned char* __restrict__ um_raw,
                     unsigned char* __restrict__ wsb) {
    if (blockIdx.x < 192) {
        int idx = blockIdx.x * 256 + threadIdx.x;   // < 49152 = 3*128*128
        int l = idx >> 14, r = idx & 16383, o = r >> 7, c = r & 127;
        float w = Ws[idx];
        unsigned short hi = f2bf_rn(w);
        unsigned short lo = f2bf_rn(w - bf2f(hi));
        int mt = o >> 4, lm = o & 15, ks = c >> 5, kr = c & 31, q = kr >> 3, j = kr & 7;
        int lane = q * 16 + lm;
        int di = ((((l * 8 + mt) * 4 + ks) * 64 + lane) << 3) + j;
        ((unsigned short*)(wsb + WA_HI))[di] = hi;
        ((unsigned short*)(wsb + WA_LO))[di] = lo;
        return;
    }
    int b = threadIdx.x;
    if (b >= B_) return;

    bool is_bool = false;
    for (int i = 0; i < 32; ++i)
        if ((i & 3) && um_raw[i]) is_bool = true;
    bool um = is_bool ? (um_raw[b] != 0) : (((const int*)um_raw)[b] != 0);
    int mi = mem_idx[b];

    float a[16];
#pragma unroll
    for (int i = 0; i < 16; ++i)
        a[i] = um ? prev_ext[mi * 16 + i] : ((i % 5 == 0) ? 1.f : 0.f);

    float s0 = a[0]*a[5]  - a[1]*a[4];
    float s1 = a[0]*a[6]  - a[2]*a[4];
    float s2 = a[0]*a[7]  - a[3]*a[4];
    float s3 = a[1]*a[6]  - a[2]*a[5];
    float s4 = a[1]*a[7]  - a[3]*a[5];
    float s5 = a[2]*a[7]  - a[3]*a[6];
    float c5 = a[10]*a[15] - a[11]*a[14];
    float c4 = a[9]*a[15]  - a[11]*a[13];
    float c3 = a[9]*a[14]  - a[10]*a[13];
    float c2 = a[8]*a[15]  - a[11]*a[12];
    float c1 = a[8]*a[14]  - a[10]*a[12];
    float c0 = a[8]*a[13]  - a[9]*a[12];
    float det = s0*c5 - s1*c4 + s2*c3 + s3*c2 - s4*c1 + s5*c0;
    float id = 1.0f / det;

    float inv[16];
    inv[0]  = ( a[5]*c5  - a[6]*c4  + a[7]*c3)  * id;
    inv[1]  = (-a[1]*c5  + a[2]*c4  - a[3]*c3)  * id;
    inv[2]  = ( a[13]*s5 - a[14]*s4 + a[15]*s3) * id;
    inv[3]  = (-a[9]*s5  + a[10]*s4 - a[11]*s3) * id;
    inv[4]  = (-a[4]*c5  + a[6]*c2  - a[7]*c1)  * id;
    inv[5]  = ( a[0]*c5  - a[2]*c2  + a[3]*c1)  * id;
    inv[6]  = (-a[12]*s5 + a[14]*s2 - a[15]*s1) * id;
    inv[7]  = ( a[8]*s5  - a[10]*s2 + a[11]*s1) * id;
    inv[8]  = ( a[4]*c4  - a[5]*c2  + a[7]*c0)  * id;
    inv[9]  = (-a[0]*c4  + a[1]*c2  - a[3]*c0)  * id;
    inv[10] = ( a[12]*s4 - a[13]*s2 + a[15]*s0) * id;
    inv[11] = (-a[8]*s4  + a[9]*s2  - a[11]*s0) * id;
    inv[12] = (-a[4]*c3  + a[5]*c1  - a[6]*c0)  * id;
    inv[13] = ( a[0]*c3  - a[1]*c1  + a[2]*c0)  * id;
    inv[14] = (-a[12]*s3 + a[13]*s1 - a[14]*s0) * id;
    inv[15] = ( a[8]*s3  - a[9]*s1  + a[10]*s0) * id;

    float* xf = (float*)(wsb + XF_OFF) + b * 16;
#pragma unroll
    for (int i = 0; i < 4; ++i)
#pragma unroll
        for (int j2 = 0; j2 < 4; ++j2) {
            float s = 0.f;
#pragma unroll
            for (int k = 0; k < 4; ++k)
                s += cur_ext[b * 16 + i * 4 + k] * inv[k * 4 + j2];
            xf[i * 4 + j2] = s;
        }
    ((float*)(wsb + UM_OFF))[b] = um ? 1.f : 0.f;
}

// ---------------------------------------------------------------------------
// fused_main: 128-px tile, 512 threads (8 waves). x staged in LDS in exact
// MFMA B-fragment order (reads are lane-linear ds_read_b128 -> conflict-free).
// 3 layers of split-bf16 MFMA (hh + lh + hl), in-place frag update.
// Wave w (layers 0/1): mt-pair = 2*(w&3), nt range = 4*(w>>2)..+3.
// Wave w (layer 2):   mt = 4 + (w&3),    nt range = 4*(w>>2)..+3.
// ---------------------------------------------------------------------------
__global__ __launch_bounds__(512, 4)
void fused_main(const float* __restrict__ img, const float* __restrict__ mem,
                const int* __restrict__ mem_idx, const float* __restrict__ bs,
                const unsigned char* __restrict__ wsb, float* __restrict__ out) {
    __shared__ unsigned short xh[32 * FS]; // 33280 B
    __shared__ unsigned short xl[32 * FS]; // 33280 B

    const int t   = threadIdx.x;
    const int b   = blockIdx.y;
    const int hw0 = blockIdx.x * P_TILE;
    const bool umb = ((const float*)(wsb + UM_OFF))[b] != 0.f;
    const int mi  = mem_idx[b];

    const bf16x8* __restrict__ WH = (const bf16x8*)(wsb + WA_HI);
    const bf16x8* __restrict__ WL = (const bf16x8*)(wsb + WA_LO);

    const int w    = t >> 6;
    const int lane = t & 63;

    // ---- stage: global f32 -> (FTL) -> truncation-split bf16 hi/lo, frag order ----
    {
        const int px = lane + 64 * (w & 1);  // 0..127, wave-contiguous for coalescing
        const int cq = t >> 7;               // 0..3
        float xfv[16];
        if (umb) {
            const float* xfp = (const float*)(wsb + XF_OFF) + b * 16;
#pragma unroll
            for (int i = 0; i < 16; ++i) xfv[i] = xfp[i];
        }
        const int pstart = umb ? 0 : 4;
        for (int p = pstart; p < 8; ++p) {
            int gg = p * 4 + cq;             // channel group 0..31
            int c0 = gg * 4;
            const float* src = (c0 < 64)
                ? (mem + ((size_t)mi * 64 + c0) * HW_ + hw0 + px)
                : (img + ((size_t)b  * 64 + (c0 - 64)) * HW_ + hw0 + px);
            float v0 = src[0], v1 = src[HW_], v2 = src[2 * HW_], v3 = src[3 * HW_];
            if (umb && gg < 8) {
                float r0 = xfv[0]  * v0 + xfv[1]  * v1 + xfv[2]  * v2 + xfv[3]  * v3;
                float r1 = xfv[4]  * v0 + xfv[5]  * v1 + xfv[6]  * v2 + xfv[7]  * v3;
                float r2 = xfv[8]  * v0 + xfv[9]  * v1 + xfv[10] * v2 + xfv[11] * v3;
                float r3 = xfv[12] * v0 + xfv[13] * v1 + xfv[14] * v2 + xfv[15] * v3;
                v0 = r0; v1 = r1; v2 = r2; v3 = r3;
            }
            unsigned u0 = __float_as_uint(v0), u1 = __float_as_uint(v1);
            unsigned u2 = __float_as_uint(v2), u3 = __float_as_uint(v3);
            unsigned l0 = __float_as_uint(v0 - __uint_as_float(u0 & 0xFFFF0000u));
            unsigned l1 = __float_as_uint(v1 - __uint_as_float(u1 & 0xFFFF0000u));
            unsigned l2 = __float_as_uint(v2 - __uint_as_float(u2 & 0xFFFF0000u));
            unsigned l3 = __float_as_uint(v3 - __uint_as_float(u3 & 0xFFFF0000u));
            uint2 hp = make_uint2(__builtin_amdgcn_perm(u1, u0, 0x07060302u),
                                  __builtin_amdgcn_perm(u3, u2, 0x07060302u));
            uint2 lp = make_uint2(__builtin_amdgcn_perm(l1, l0, 0x07060302u),
                                  __builtin_amdgcn_perm(l3, l2, 0x07060302u));
            // fragment-order address: (px,c) -> frag(px>>4, c>>5), lane ((c&31)>>3)*16 + (px&15), j c&7
            int addr = FOFF(px >> 4, c0 >> 5) + (((c0 & 31) >> 3) * 16 + (px & 15)) * 8 + (c0 & 7);
            *(uint2*)&xh[addr] = hp;
            *(uint2*)&xl[addr] = lp;
        }
    }
    __syncthreads();

    const int wq = lane >> 4;  // 0..3
    const int lm = lane & 15;

    // ---- layers 0,1: full 128 outputs, ReLU, write back to LDS (frag order) ----
    const int mt0 = 2 * (w & 3);
    const int nt0 = 4 * (w >> 2);
#pragma unroll
    for (int l = 0; l < 2; ++l) {
        f32x4 acc[2][4];
#pragma unroll
        for (int mi2 = 0; mi2 < 2; ++mi2) {
            f32x4 bv = *(const f32x4*)&bs[l * NC + (mt0 + mi2) * 16 + wq * 4];
#pragma unroll
            for (int nt = 0; nt < 4; ++nt) acc[mi2][nt] = bv;
        }
        auto do_ks = [&](int ks) {
            int f0 = ((l * 8 + mt0) * 4 + ks) * 64 + lane;
            int f1 = f0 + 4 * 64;
            bf16x8 ah0 = WH[f0], al0 = WL[f0];
            bf16x8 ah1 = WH[f1], al1 = WL[f1];
#pragma unroll
            for (int nt = 0; nt < 4; ++nt) {
                int ba = FOFF(nt0 + nt, ks) + lane * 8;
                bf16x8 bh = *(const bf16x8*)&xh[ba];
                bf16x8 bl = *(const bf16x8*)&xl[ba];
                acc[0][nt] = __builtin_amdgcn_mfma_f32_16x16x32_bf16(ah0, bh, acc[0][nt], 0, 0, 0);
                acc[1][nt] = __builtin_amdgcn_mfma_f32_16x16x32_bf16(ah1, bh, acc[1][nt], 0, 0, 0);
                acc[0][nt] = __builtin_amdgcn_mfma_f32_16x16x32_bf16(al0, bh, acc[0][nt], 0, 0, 0);
                acc[1][nt] = __builtin_amdgcn_mfma_f32_16x16x32_bf16(al1, bh, acc[1][nt], 0, 0, 0);
                acc[0][nt] = __builtin_amdgcn_mfma_f32_16x16x32_bf16(ah0, bl, acc[0][nt], 0, 0, 0);
                acc[1][nt] = __builtin_amdgcn_mfma_f32_16x16x32_bf16(ah1, bl, acc[1][nt], 0, 0, 0);
            }
        };
        if (l == 0 && !umb) { do_ks(2); do_ks(3); }
        else { do_ks(0); do_ks(1); do_ks(2); do_ks(3); }

        __syncthreads(); // all reads of x done before overwrite
#pragma unroll
        for (int mi2 = 0; mi2 < 2; ++mi2) {
            int mt = mt0 + mi2;
            int ks2 = mt >> 1;
            int lane_f = ((mt & 1) * 2 + (wq >> 1)) * 16 + lm;
            int j0 = (wq & 1) * 4;
#pragma unroll
            for (int nt = 0; nt < 4; ++nt) {
                float v0 = fmaxf(acc[mi2][nt][0], 0.f);
                float v1 = fmaxf(acc[mi2][nt][1], 0.f);
                float v2 = fmaxf(acc[mi2][nt][2], 0.f);
                float v3 = fmaxf(acc[mi2][nt][3], 0.f);
                unsigned u0 = __float_as_uint(v0), u1 = __float_as_uint(v1);
                unsigned u2 = __float_as_uint(v2), u3 = __float_as_uint(v3);
                unsigned l0 = __float_as_uint(v0 - __uint_as_float(u0 & 0xFFFF0000u));
                unsigned l1 = __float_as_uint(v1 - __uint_as_float(u1 & 0xFFFF0000u));
                unsigned l2 = __float_as_uint(v2 - __uint_as_float(u2 & 0xFFFF0000u));
                unsigned l3 = __float_as_uint(v3 - __uint_as_float(u3 & 0xFFFF0000u));
                int addr = FOFF(nt0 + nt, ks2) + lane_f * 8 + j0;
                *(uint2*)&xh[addr] =
                    make_uint2(__builtin_amdgcn_perm(u1, u0, 0x07060302u),
                               __builtin_amdgcn_perm(u3, u2, 0x07060302u));
                *(uint2*)&xl[addr] =
                    make_uint2(__builtin_amdgcn_perm(l1, l0, 0x07060302u),
                               __builtin_amdgcn_perm(l3, l2, 0x07060302u));
            }
        }
        __syncthreads();
    }

    // ---- layer 2: out channels 64..127 only, straight to global ----
    {
        const int mt2 = 4 + (w & 3);
        f32x4 acc[4];
        f32x4 bv = *(const f32x4*)&bs[2 * NC + mt2 * 16 + wq * 4];
#pragma unroll
        for (int nt = 0; nt < 4; ++nt) acc[nt] = bv;
#pragma unroll
        for (int ks = 0; ks < 4; ++ks) {
            int f = ((2 * 8 + mt2) * 4 + ks) * 64 + lane;
            bf16x8 ah = WH[f], al = WL[f];
#pragma unroll
            for (int nt = 0; nt < 4; ++nt) {
                int ba = FOFF(nt0 + nt, ks) + lane * 8;
                bf16x8 bh = *(const bf16x8*)&xh[ba];
                bf16x8 bl = *(const bf16x8*)&xl[ba];
                acc[nt] = __builtin_amdgcn_mfma_f32_16x16x32_bf16(ah, bh, acc[nt], 0, 0, 0);
                acc[nt] = __builtin_amdgcn_mfma_f32_16x16x32_bf16(al, bh, acc[nt], 0, 0, 0);
                acc[nt] = __builtin_amdgcn_mfma_f32_16x16x32_bf16(ah, bl, acc[nt], 0, 0, 0);
            }
        }
        const int oc0 = mt2 * 16 + wq * 4 - 64; // 0..63
#pragma unroll
        for (int nt = 0; nt < 4; ++nt) {
            float* dst = out + ((size_t)b * 64 + oc0) * HW_ + hw0 + (nt0 + nt) * 16 + lm;
#pragma unroll
            for (int r = 0; r < 4; ++r)
                dst[(size_t)r * HW_] = acc[nt][r];
        }
    }
}

extern "C" void kernel_launch(void* const* d_in, const int* in_sizes, int n_in,
                              void* d_out, int out_size, void* d_ws, size_t ws_size,
                              hipStream_t stream) {
    const float* img  = (const float*)d_in[0];
    const float* mem  = (const float*)d_in[1];
    const float* pext = (const float*)d_in[2];
    const float* cext = (const float*)d_in[3];
    const int*   midx = (const int*)d_in[4];
    const unsigned char* umem = (const unsigned char*)d_in[5];
    const float* Ws   = (const float*)d_in[6];
    const float* bs   = (const float*)d_in[7];
    float* out = (float*)d_out;
    unsigned char* wsb = (unsigned char*)d_ws;

    hipLaunchKernelGGL(prep, dim3(193), dim3(256), 0, stream,
                       Ws, pext, cext, midx, umem, wsb);
    hipLaunchKernelGGL(fused_main, dim3(NTILES, B_), dim3(512), 0, stream,
                       img, mem, midx, bs, wsb, out);
}

// Round 5
// 171.523 us; speedup vs baseline: 1.0310x; 1.0310x over previous
//
#include <hip/hip_runtime.h>
#include <hip/hip_fp16.h>

#define NC_MEM 64
#define NC_IMG 64
#define NC     128
#define B_     32
#define H_     64
#define W_     96
#define HW_    (H_ * W_)      // 6144
#define P_TILE 128
#define NTILES (HW_ / P_TILE) // 48
#define FS     520            // frag stride in ushorts: 512 + 8 pad (16B-aligned rows)
#define FOFF(pt, ks) ((((pt) * 4) + (ks)) * FS)

// d_ws byte layout
#define WA_HI  0                       // ushort[3][8][4][64][8] = 98304 B (f16 hi, A-fragment order)
#define WA_LO  98304                   // same, f16 lo (w - f16(w))
#define XF_OFF 196608                  // float[32][16]
#define UM_OFF 198656                  // float[32]

typedef _Float16 f16x8 __attribute__((ext_vector_type(8)));
typedef __attribute__((ext_vector_type(4))) float f32x4;

__device__ inline unsigned pk2h(float a, float b) {
    __half2 h = __floats2half2_rn(a, b);
    return *(const unsigned*)&h;
}

// ---------------------------------------------------------------------------
// prep: blocks 0..191 split W into f16 hi/lo (hi=f16(w), lo=f16(w-hi): 22-bit
// effective mantissa -> W is effectively exact) in MFMA A-fragment order;
// block 192 computes xf via closed-form adjugate inverse + decodes use_memory.
// ---------------------------------------------------------------------------
__global__ void prep(const float* __restrict__ Ws,
                     const float* __restrict__ prev_ext,
                     const float* __restrict__ cur_ext,
                     const int* __restrict__ mem_idx,
                     const unsigned char* __restrict__ um_raw,
                     unsigned char* __restrict__ wsb) {
    if (blockIdx.x < 192) {
        int idx = blockIdx.x * 256 + threadIdx.x;   // < 49152 = 3*128*128
        int l = idx >> 14, r = idx & 16383, o = r >> 7, c = r & 127;
        float w = Ws[idx];
        __half hi = __float2half_rn(w);
        __half lo = __float2half_rn(w - __half2float(hi));
        int mt = o >> 4, lm = o & 15, ks = c >> 5, kr = c & 31, q = kr >> 3, j = kr & 7;
        int lane = q * 16 + lm;
        int di = ((((l * 8 + mt) * 4 + ks) * 64 + lane) << 3) + j;
        ((unsigned short*)(wsb + WA_HI))[di] = __half_as_ushort(hi);
        ((unsigned short*)(wsb + WA_LO))[di] = __half_as_ushort(lo);
        return;
    }
    int b = threadIdx.x;
    if (b >= B_) return;

    bool is_bool = false;
    for (int i = 0; i < 32; ++i)
        if ((i & 3) && um_raw[i]) is_bool = true;
    bool um = is_bool ? (um_raw[b] != 0) : (((const int*)um_raw)[b] != 0);
    int mi = mem_idx[b];

    float a[16];
#pragma unroll
    for (int i = 0; i < 16; ++i)
        a[i] = um ? prev_ext[mi * 16 + i] : ((i % 5 == 0) ? 1.f : 0.f);

    float s0 = a[0]*a[5]  - a[1]*a[4];
    float s1 = a[0]*a[6]  - a[2]*a[4];
    float s2 = a[0]*a[7]  - a[3]*a[4];
    float s3 = a[1]*a[6]  - a[2]*a[5];
    float s4 = a[1]*a[7]  - a[3]*a[5];
    float s5 = a[2]*a[7]  - a[3]*a[6];
    float c5 = a[10]*a[15] - a[11]*a[14];
    float c4 = a[9]*a[15]  - a[11]*a[13];
    float c3 = a[9]*a[14]  - a[10]*a[13];
    float c2 = a[8]*a[15]  - a[11]*a[12];
    float c1 = a[8]*a[14]  - a[10]*a[12];
    float c0 = a[8]*a[13]  - a[9]*a[12];
    float det = s0*c5 - s1*c4 + s2*c3 + s3*c2 - s4*c1 + s5*c0;
    float id = 1.0f / det;

    float inv[16];
    inv[0]  = ( a[5]*c5  - a[6]*c4  + a[7]*c3)  * id;
    inv[1]  = (-a[1]*c5  + a[2]*c4  - a[3]*c3)  * id;
    inv[2]  = ( a[13]*s5 - a[14]*s4 + a[15]*s3) * id;
    inv[3]  = (-a[9]*s5  + a[10]*s4 - a[11]*s3) * id;
    inv[4]  = (-a[4]*c5  + a[6]*c2  - a[7]*c1)  * id;
    inv[5]  = ( a[0]*c5  - a[2]*c2  + a[3]*c1)  * id;
    inv[6]  = (-a[12]*s5 + a[14]*s2 - a[15]*s1) * id;
    inv[7]  = ( a[8]*s5  - a[10]*s2 + a[11]*s1) * id;
    inv[8]  = ( a[4]*c4  - a[5]*c2  + a[7]*c0)  * id;
    inv[9]  = (-a[0]*c4  + a[1]*c2  - a[3]*c0)  * id;
    inv[10] = ( a[12]*s4 - a[13]*s2 + a[15]*s0) * id;
    inv[11] = (-a[8]*s4  + a[9]*s2  - a[11]*s0) * id;
    inv[12] = (-a[4]*c3  + a[5]*c1  - a[6]*c0)  * id;
    inv[13] = ( a[0]*c3  - a[1]*c1  + a[2]*c0)  * id;
    inv[14] = (-a[12]*s3 + a[13]*s1 - a[14]*s0) * id;
    inv[15] = ( a[8]*s3  - a[9]*s1  + a[10]*s0) * id;

    float* xf = (float*)(wsb + XF_OFF) + b * 16;
#pragma unroll
    for (int i = 0; i < 4; ++i)
#pragma unroll
        for (int j2 = 0; j2 < 4; ++j2) {
            float s = 0.f;
#pragma unroll
            for (int k = 0; k < 4; ++k)
                s += cur_ext[b * 16 + i * 4 + k] * inv[k * 4 + j2];
            xf[i * 4 + j2] = s;
        }
    ((float*)(wsb + UM_OFF))[b] = um ? 1.f : 0.f;
}

// ---------------------------------------------------------------------------
// fused_main: 128-px tile, 512 threads (8 waves). x staged as SINGLE f16 tile
// in MFMA B-fragment order (lane-linear ds_read_b128, conflict-free).
// Each layer: out = wh (.) x + wl (.) x  -- 2 MFMAs per 16x16 tile.
// Wave w (layers 0/1): mt-pair = 2*(w&3), nt range = 4*(w>>2)..+3.
// Wave w (layer 2):   mt = 4 + (w&3),    nt range = 4*(w>>2)..+3.
// ---------------------------------------------------------------------------
__global__ __launch_bounds__(512, 4)
void fused_main(const float* __restrict__ img, const float* __restrict__ mem,
                const int* __restrict__ mem_idx, const float* __restrict__ bs,
                const unsigned char* __restrict__ wsb, float* __restrict__ out) {
    __shared__ unsigned short xh[32 * FS]; // 33280 B -> 4 blocks/CU

    const int t   = threadIdx.x;
    const int b   = blockIdx.y;
    const int hw0 = blockIdx.x * P_TILE;
    const bool umb = ((const float*)(wsb + UM_OFF))[b] != 0.f;
    const int mi  = mem_idx[b];

    const f16x8* __restrict__ WH = (const f16x8*)(wsb + WA_HI);
    const f16x8* __restrict__ WL = (const f16x8*)(wsb + WA_LO);

    const int w    = t >> 6;
    const int lane = t & 63;

    // ---- stage: global f32 -> (FTL) -> f16 in LDS (B-fragment order) ----
    {
        const int px = lane + 64 * (w & 1);  // 0..127, wave-contiguous for coalescing
        const int cq = t >> 7;               // 0..3
        float xfv[16];
        if (umb) {
            const float* xfp = (const float*)(wsb + XF_OFF) + b * 16;
#pragma unroll
            for (int i = 0; i < 16; ++i) xfv[i] = xfp[i];
        }
        const int pstart = umb ? 0 : 4;
        for (int p = pstart; p < 8; ++p) {
            int gg = p * 4 + cq;             // channel group 0..31
            int c0 = gg * 4;
            const float* src = (c0 < 64)
                ? (mem + ((size_t)mi * 64 + c0) * HW_ + hw0 + px)
                : (img + ((size_t)b  * 64 + (c0 - 64)) * HW_ + hw0 + px);
            float v0 = src[0], v1 = src[HW_], v2 = src[2 * HW_], v3 = src[3 * HW_];
            if (umb && gg < 8) {
                float r0 = xfv[0]  * v0 + xfv[1]  * v1 + xfv[2]  * v2 + xfv[3]  * v3;
                float r1 = xfv[4]  * v0 + xfv[5]  * v1 + xfv[6]  * v2 + xfv[7]  * v3;
                float r2 = xfv[8]  * v0 + xfv[9]  * v1 + xfv[10] * v2 + xfv[11] * v3;
                float r3 = xfv[12] * v0 + xfv[13] * v1 + xfv[14] * v2 + xfv[15] * v3;
                v0 = r0; v1 = r1; v2 = r2; v3 = r3;
            }
            // fragment-order address: (px,c) -> frag(px>>4, c>>5), lane ((c&31)>>3)*16+(px&15), j c&7
            int addr = FOFF(px >> 4, c0 >> 5) + (((c0 & 31) >> 3) * 16 + (px & 15)) * 8 + (c0 & 7);
            *(uint2*)&xh[addr] = make_uint2(pk2h(v0, v1), pk2h(v2, v3));
        }
    }
    __syncthreads();

    const int wq = lane >> 4;  // 0..3
    const int lm = lane & 15;

    // ---- layers 0,1: full 128 outputs, ReLU, write back to LDS (frag order) ----
    const int mt0 = 2 * (w & 3);
    const int nt0 = 4 * (w >> 2);
#pragma unroll
    for (int l = 0; l < 2; ++l) {
        f32x4 acc[2][4];
#pragma unroll
        for (int mi2 = 0; mi2 < 2; ++mi2) {
            f32x4 bv = *(const f32x4*)&bs[l * NC + (mt0 + mi2) * 16 + wq * 4];
#pragma unroll
            for (int nt = 0; nt < 4; ++nt) acc[mi2][nt] = bv;
        }
        auto do_ks = [&](int ks) {
            int f0 = ((l * 8 + mt0) * 4 + ks) * 64 + lane;
            int f1 = f0 + 4 * 64;
            f16x8 ah0 = WH[f0], al0 = WL[f0];
            f16x8 ah1 = WH[f1], al1 = WL[f1];
#pragma unroll
            for (int nt = 0; nt < 4; ++nt) {
                f16x8 bh = *(const f16x8*)&xh[FOFF(nt0 + nt, ks) + lane * 8];
                acc[0][nt] = __builtin_amdgcn_mfma_f32_16x16x32_f16(ah0, bh, acc[0][nt], 0, 0, 0);
                acc[1][nt] = __builtin_amdgcn_mfma_f32_16x16x32_f16(ah1, bh, acc[1][nt], 0, 0, 0);
                acc[0][nt] = __builtin_amdgcn_mfma_f32_16x16x32_f16(al0, bh, acc[0][nt], 0, 0, 0);
                acc[1][nt] = __builtin_amdgcn_mfma_f32_16x16x32_f16(al1, bh, acc[1][nt], 0, 0, 0);
            }
        };
        if (l == 0 && !umb) { do_ks(2); do_ks(3); }
        else { do_ks(0); do_ks(1); do_ks(2); do_ks(3); }

        __syncthreads(); // all reads of x done before overwrite
#pragma unroll
        for (int mi2 = 0; mi2 < 2; ++mi2) {
            int mt = mt0 + mi2;
            int ks2 = mt >> 1;
            int lane_f = ((mt & 1) * 2 + (wq >> 1)) * 16 + lm;
            int j0 = (wq & 1) * 4;
#pragma unroll
            for (int nt = 0; nt < 4; ++nt) {
                float v0 = fmaxf(acc[mi2][nt][0], 0.f);
                float v1 = fmaxf(acc[mi2][nt][1], 0.f);
                float v2 = fmaxf(acc[mi2][nt][2], 0.f);
                float v3 = fmaxf(acc[mi2][nt][3], 0.f);
                int addr = FOFF(nt0 + nt, ks2) + lane_f * 8 + j0;
                *(uint2*)&xh[addr] = make_uint2(pk2h(v0, v1), pk2h(v2, v3));
            }
        }
        __syncthreads();
    }

    // ---- layer 2: out channels 64..127 only, straight to global ----
    {
        const int mt2 = 4 + (w & 3);
        f32x4 acc[4];
        f32x4 bv = *(const f32x4*)&bs[2 * NC + mt2 * 16 + wq * 4];
#pragma unroll
        for (int nt = 0; nt < 4; ++nt) acc[nt] = bv;
#pragma unroll
        for (int ks = 0; ks < 4; ++ks) {
            int f = ((2 * 8 + mt2) * 4 + ks) * 64 + lane;
            f16x8 ah = WH[f], al = WL[f];
#pragma unroll
            for (int nt = 0; nt < 4; ++nt) {
                f16x8 bh = *(const f16x8*)&xh[FOFF(nt0 + nt, ks) + lane * 8];
                acc[nt] = __builtin_amdgcn_mfma_f32_16x16x32_f16(ah, bh, acc[nt], 0, 0, 0);
                acc[nt] = __builtin_amdgcn_mfma_f32_16x16x32_f16(al, bh, acc[nt], 0, 0, 0);
            }
        }
        const int oc0 = mt2 * 16 + wq * 4 - 64; // 0..63
#pragma unroll
        for (int nt = 0; nt < 4; ++nt) {
            float* dst = out + ((size_t)b * 64 + oc0) * HW_ + hw0 + (nt0 + nt) * 16 + lm;
#pragma unroll
            for (int r = 0; r < 4; ++r)
                dst[(size_t)r * HW_] = acc[nt][r];
        }
    }
}

extern "C" void kernel_launch(void* const* d_in, const int* in_sizes, int n_in,
                              void* d_out, int out_size, void* d_ws, size_t ws_size,
                              hipStream_t stream) {
    const float* img  = (const float*)d_in[0];
    const float* mem  = (const float*)d_in[1];
    const float* pext = (const float*)d_in[2];
    const float* cext = (const float*)d_in[3];
    const int*   midx = (const int*)d_in[4];
    const unsigned char* umem = (const unsigned char*)d_in[5];
    const float* Ws   = (const float*)d_in[6];
    const float* bs   = (const float*)d_in[7];
    float* out = (float*)d_out;
    unsigned char* wsb = (unsigned char*)d_ws;

    hipLaunchKernelGGL(prep, dim3(193), dim3(256), 0, stream,
                       Ws, pext, cext, midx, umem, wsb);
    hipLaunchKernelGGL(fused_main, dim3(NTILES, B_), dim3(512), 0, stream,
                       img, mem, midx, bs, wsb, out);
}